// Round 3
// baseline (288.196 us; speedup 1.0000x reference)
//
#include <hip/hip_runtime.h>
#include <cstddef>

#define EPS 1e-5f
static constexpr int Bn = 64, Cn = 64, Hn = 56, Wn = 56, HWn = Hn * Wn; // 3136
static constexpr int STR = 136;  // LDS cat row stride (shorts): 272B = 68 dwords, 16B-aligned, bank-balanced

typedef __attribute__((ext_vector_type(8))) short short8;
typedef __attribute__((ext_vector_type(4))) short short4v;
typedef __attribute__((ext_vector_type(4))) float floatx4;

__device__ __forceinline__ unsigned short f2bf(float f) {
    unsigned u = __float_as_uint(f);
    return (unsigned short)((u + 0x7fffu + ((u >> 16) & 1u)) >> 16); // RNE
}
__device__ __forceinline__ float bf2f(unsigned short s) {
    return __uint_as_float(((unsigned)s) << 16);
}

// ---------------------------------------------------------------------------
// K1: node0[p][c] (pixel-major bf16) = relu(bn1(conv1x1(x, w1)))
// Per wave: D[64 o][16 px] via 8 MFMAs; no LDS in the main loop, no barriers.
// Epilogue: direct 8B bf16 stores (4 consecutive c per lane).
// ---------------------------------------------------------------------------
__global__ __launch_bounds__(256) void k1_conv1(
    const float* __restrict__ x, const float* __restrict__ w1,
    const float* __restrict__ bg, const float* __restrict__ bb,
    const float* __restrict__ bm, const float* __restrict__ bv,
    unsigned short* __restrict__ node0)
{
    __shared__ float scs[64], shs[64];
    const int tid = threadIdx.x;
    if (tid < 64) {
        float sc = bg[tid] * rsqrtf(bv[tid] + EPS);
        scs[tid] = sc;
        shs[tid] = bb[tid] - bm[tid] * sc;
    }
    const int lane = tid & 63;
    const int wv   = tid >> 6;
    const int m    = lane & 15;
    const int quad = lane >> 4;

    // A-frags: w1[o][k], lane holds row o = t*16+m, k = kk*32 + quad*8 + j
    short8 afr[4][2];
    #pragma unroll
    for (int t = 0; t < 4; ++t) {
        #pragma unroll
        for (int kk = 0; kk < 2; ++kk) {
            const float* wp = w1 + (t * 16 + m) * 64 + kk * 32 + quad * 8;
            floatx4 f0 = *(const floatx4*)wp;
            floatx4 f1 = *(const floatx4*)(wp + 4);
            short8 s;
            s[0] = (short)f2bf(f0[0]); s[1] = (short)f2bf(f0[1]);
            s[2] = (short)f2bf(f0[2]); s[3] = (short)f2bf(f0[3]);
            s[4] = (short)f2bf(f1[0]); s[5] = (short)f2bf(f1[1]);
            s[6] = (short)f2bf(f1[2]); s[7] = (short)f2bf(f1[3]);
            afr[t][kk] = s;
        }
    }
    __syncthreads();

    #pragma unroll
    for (int tt = 0; tt < 4; ++tt) {
        const long P0 = (long)blockIdx.x * 256 + tt * 64; // 64-px group per tt (4 waves x 16)
        const int b = (int)(P0 / HWn);
        const int p = (int)(P0 - (long)b * HWn) + wv * 16 + m;

        floatx4 acc[4];
        #pragma unroll
        for (int t = 0; t < 4; ++t) acc[t] = (floatx4){0.f, 0.f, 0.f, 0.f};

        #pragma unroll
        for (int kk = 0; kk < 2; ++kk) {
            short8 bfr;
            #pragma unroll
            for (int j = 0; j < 8; ++j) {
                int c = kk * 32 + quad * 8 + j;
                bfr[j] = (short)f2bf(x[(size_t)(b * 64 + c) * HWn + p]);
            }
            #pragma unroll
            for (int t = 0; t < 4; ++t)
                acc[t] = __builtin_amdgcn_mfma_f32_16x16x32_bf16(afr[t][kk], bfr, acc[t], 0, 0, 0);
        }

        const size_t px = (size_t)P0 + wv * 16 + m;
        #pragma unroll
        for (int t = 0; t < 4; ++t) {
            short4v st;
            #pragma unroll
            for (int i = 0; i < 4; ++i) {
                int o = t * 16 + quad * 4 + i;
                float v = fmaf(acc[t][i], scs[o], shs[o]);
                st[i] = (short)f2bf(v > 0.f ? v : 0.f);
            }
            *(short4v*)(node0 + px * 64 + t * 16 + quad * 4) = st;
        }
    }
}

// ---------------------------------------------------------------------------
// K23 fused: pools -> LDS cat tile -> conv2 MFMA -> out.
// Block = (b, 4-row band), 512 thr. Pool: wave=8-ch chunk, lane=col, rolling
// rings, writes bf16 cat tile [224 px][STR] to LDS. Then 7 waves x 2 px-tiles
// of 16: B-frags via aligned ds_read_b128, A=w2 regs, direct fp32 stores.
// ---------------------------------------------------------------------------
__global__ __launch_bounds__(512, 4) void k23_fused(
    const unsigned short* __restrict__ node0, const float* __restrict__ w2,
    const float* __restrict__ bg, const float* __restrict__ bb,
    const float* __restrict__ bm, const float* __restrict__ bv,
    float* __restrict__ out)
{
    __shared__ unsigned short ct[224 * STR];  // 60928 B
    __shared__ float scs[64], shs[64];
    const int tid = threadIdx.x;
    if (tid < 64) {
        float sc = bg[tid] * rsqrtf(bv[tid] + EPS);
        scs[tid] = sc;
        shs[tid] = bb[tid] - bm[tid] * sc;
    }
    const int lane  = tid & 63;
    const int wv    = tid >> 6;     // wave = channel chunk in pool phase
    const int col   = lane;
    const int chunk = wv;
    const bool act  = col < Wn;
    const int b    = blockIdx.x / 14;
    const int band = blockIdx.x % 14;
    const int lo = band * 4, hi = lo + 4;
    const unsigned short* base = node0 + (size_t)b * HWn * 64 + chunk * 8;

    float hs1[8], hs2[8], h5a[8], h5b[8], h5c[8], h5d[8], nh1[8], nh2[8];
    #pragma unroll
    for (int j = 0; j < 8; ++j) {
        hs1[j] = hs2[j] = 0.f;
        h5a[j] = h5b[j] = h5c[j] = h5d[j] = 0.f;
        nh1[j] = nh2[j] = 0.f;
    }

    for (int r = lo - 2; r <= lo + 5; ++r) {
        float v[5][8];
        #pragma unroll
        for (int d = 0; d < 5; ++d) {
            int cc = col + d - 2;
            bool ok = act && ((unsigned)cc < (unsigned)Wn) && ((unsigned)r < (unsigned)Hn);
            if (ok) {
                short8 ld = *(const short8*)(base + (size_t)(r * Wn + cc) * 64);
                #pragma unroll
                for (int j = 0; j < 8; ++j) v[d][j] = bf2f((unsigned short)ld[j]);
            } else {
                #pragma unroll
                for (int j = 0; j < 8; ++j) v[d][j] = 0.f;
            }
        }
        float a2[8], m5[8], m3[8];
        const int r2 = r - 1, r3 = r - 2;
        const bool v2 = (unsigned)r2 < (unsigned)Hn;
        #pragma unroll
        for (int j = 0; j < 8; ++j) {
            float hsum = v[1][j] + v[2][j] + v[3][j];
            float hm5 = fmaxf(fmaxf(fmaxf(v[0][j], v[1][j]), fmaxf(v[2][j], v[3][j])), v[4][j]);
            a2[j] = v2 ? (hs2[j] + hs1[j] + hsum) * (1.f / 9.f) : 0.f;
            hs2[j] = hs1[j]; hs1[j] = hsum;
            m5[j] = fmaxf(fmaxf(fmaxf(h5a[j], h5b[j]), fmaxf(h5c[j], h5d[j])), hm5);
            h5a[j] = h5b[j]; h5b[j] = h5c[j]; h5c[j] = h5d[j]; h5d[j] = hm5;
        }
        #pragma unroll
        for (int j = 0; j < 8; ++j) {
            float al = __shfl_up(a2[j], 1);   if (lane == 0)  al = 0.f;
            float ar = __shfl_down(a2[j], 1); if (lane == 63) ar = 0.f;
            float nh = fmaxf(fmaxf(al, a2[j]), ar);
            m3[j] = fmaxf(fmaxf(nh2[j], nh1[j]), nh);
            nh2[j] = nh1[j]; nh1[j] = nh;
        }
        if (act && r2 >= lo && r2 < hi) {
            short8 st;
            #pragma unroll
            for (int j = 0; j < 8; ++j) st[j] = (short)f2bf(a2[j]);
            *(short8*)(ct + (size_t)((r2 - lo) * 56 + col) * STR + chunk * 8) = st;
        }
        if (act && r3 >= lo && r3 < hi) {
            short8 st;
            #pragma unroll
            for (int j = 0; j < 8; ++j) st[j] = (short)f2bf(m5[j] + m3[j]);
            *(short8*)(ct + (size_t)((r3 - lo) * 56 + col) * STR + 64 + chunk * 8) = st;
        }
    }

    // --- phase B: conv2 over the 224-px LDS tile ---
    const int m    = lane & 15;
    const int quad = lane >> 4;
    short8 afr[4][4];
    if (wv < 7) {
        #pragma unroll
        for (int t = 0; t < 4; ++t) {
            #pragma unroll
            for (int kk = 0; kk < 4; ++kk) {
                const float* wp = w2 + (t * 16 + m) * 128 + kk * 32 + quad * 8;
                floatx4 f0 = *(const floatx4*)wp;
                floatx4 f1 = *(const floatx4*)(wp + 4);
                short8 s;
                s[0] = (short)f2bf(f0[0]); s[1] = (short)f2bf(f0[1]);
                s[2] = (short)f2bf(f0[2]); s[3] = (short)f2bf(f0[3]);
                s[4] = (short)f2bf(f1[0]); s[5] = (short)f2bf(f1[1]);
                s[6] = (short)f2bf(f1[2]); s[7] = (short)f2bf(f1[3]);
                afr[t][kk] = s;
            }
        }
    }
    __syncthreads();
    if (wv >= 7) return;

    #pragma unroll
    for (int s = 0; s < 2; ++s) {
        const int tile = wv * 2 + s;           // 14 tiles of 16 px
        floatx4 acc[4];
        #pragma unroll
        for (int t = 0; t < 4; ++t) acc[t] = (floatx4){0.f, 0.f, 0.f, 0.f};
        #pragma unroll
        for (int kk = 0; kk < 4; ++kk) {
            short8 bfr = *(const short8*)(ct + (size_t)(tile * 16 + m) * STR + kk * 32 + quad * 8);
            #pragma unroll
            for (int t = 0; t < 4; ++t)
                acc[t] = __builtin_amdgcn_mfma_f32_16x16x32_bf16(afr[t][kk], bfr, acc[t], 0, 0, 0);
        }
        float* ob = out + (size_t)b * 64 * HWn + lo * 56 + tile * 16 + m;
        #pragma unroll
        for (int t = 0; t < 4; ++t) {
            #pragma unroll
            for (int i = 0; i < 4; ++i) {
                int o = t * 16 + quad * 4 + i;
                float v = fmaf(acc[t][i], scs[o], shs[o]);
                ob[(size_t)o * HWn] = v > 0.f ? v : 0.f;
                // note: ob already includes px; advance per-o via o*HWn
            }
        }
    }
}

extern "C" void kernel_launch(void* const* d_in, const int* in_sizes, int n_in,
                              void* d_out, int out_size, void* d_ws, size_t ws_size,
                              hipStream_t stream)
{
    const float* x   = (const float*)d_in[0];
    const float* w1  = (const float*)d_in[1];
    const float* w2  = (const float*)d_in[2];
    const float* b1g = (const float*)d_in[3];
    const float* b1b = (const float*)d_in[4];
    const float* b1m = (const float*)d_in[5];
    const float* b1v = (const float*)d_in[6];
    const float* b2g = (const float*)d_in[7];
    const float* b2b = (const float*)d_in[8];
    const float* b2m = (const float*)d_in[9];
    const float* b2v = (const float*)d_in[10];

    float* out = (float*)d_out;
    unsigned short* node0 = (unsigned short*)d_ws;   // [B*HW][64] bf16, 25.7 MB

    k1_conv1<<<dim3(784), dim3(256), 0, stream>>>(x, w1, b1g, b1b, b1m, b1v, node0);
    k23_fused<<<dim3(Bn * 14), dim3(512), 0, stream>>>(node0, w2, b2g, b2b, b2m, b2v, out);
}

// Round 4
// 203.258 us; speedup vs baseline: 1.4179x; 1.4179x over previous
//
#include <hip/hip_runtime.h>
#include <cstddef>

#define EPS 1e-5f
static constexpr int Bn = 64, Cn = 64, Hn = 56, Wn = 56, HWn = Hn * Wn; // 3136

typedef __attribute__((ext_vector_type(8))) short short8;
typedef __attribute__((ext_vector_type(4))) float floatx4;
typedef __attribute__((ext_vector_type(16))) float floatx16;

__device__ __forceinline__ unsigned short f2bf(float f) {
    unsigned u = __float_as_uint(f);
    return (unsigned short)((u + 0x7fffu + ((u >> 16) & 1u)) >> 16); // RNE
}
__device__ __forceinline__ float bf2f(unsigned short s) {
    return __uint_as_float(((unsigned)s) << 16);
}

// Layouts (bf16):
//   node0: [b][chunk=8][px=3136][j=8]   idx = ((b*8+ch)*HWn + px)*8 + j
//   cat:   [b][chunk=16][px=3136][j=8]  ch 0-7 = avgpool, ch 8-15 = max-sum

// ---------------------------------------------------------------------------
// K1: node0 = relu(bn1(conv1x1(x, w1))), chunk-split bf16 output.
// Wave: D[64 o][16 px] via 8 MFMAs; epilogue transposes through padded LDS
// so global stores are 1-KB contiguous runs per wave.
// ---------------------------------------------------------------------------
__global__ __launch_bounds__(256) void k1_conv1(
    const float* __restrict__ x, const float* __restrict__ w1,
    const float* __restrict__ bg, const float* __restrict__ bb,
    const float* __restrict__ bm, const float* __restrict__ bv,
    unsigned short* __restrict__ node0)
{
    __shared__ unsigned short pack[64 * 88];  // 64 px rows, stride 88 shorts
    __shared__ float scs[64], shs[64];
    const int tid = threadIdx.x;
    if (tid < 64) {
        float sc = bg[tid] * rsqrtf(bv[tid] + EPS);
        scs[tid] = sc;
        shs[tid] = bb[tid] - bm[tid] * sc;
    }
    const int lane = tid & 63;
    const int wv   = tid >> 6;
    const int m    = lane & 15;
    const int quad = lane >> 4;

    // A-frags: w1[o][k], lane holds row o = t*16+m, k = kk*32 + quad*8 + j
    short8 afr[4][2];
    #pragma unroll
    for (int t = 0; t < 4; ++t) {
        #pragma unroll
        for (int kk = 0; kk < 2; ++kk) {
            const float* wp = w1 + (t * 16 + m) * 64 + kk * 32 + quad * 8;
            floatx4 f0 = *(const floatx4*)wp;
            floatx4 f1 = *(const floatx4*)(wp + 4);
            short8 s;
            s[0] = (short)f2bf(f0[0]); s[1] = (short)f2bf(f0[1]);
            s[2] = (short)f2bf(f0[2]); s[3] = (short)f2bf(f0[3]);
            s[4] = (short)f2bf(f1[0]); s[5] = (short)f2bf(f1[1]);
            s[6] = (short)f2bf(f1[2]); s[7] = (short)f2bf(f1[3]);
            afr[t][kk] = s;
        }
    }
    __syncthreads();

    for (int tt = 0; tt < 4; ++tt) {
        const long P0 = (long)blockIdx.x * 256 + tt * 64; // 64-px group, 3136%64==0
        const int b = (int)(P0 / HWn);
        const int p0 = (int)(P0 - (long)b * HWn);
        const int p = p0 + wv * 16 + m;

        floatx4 acc[4];
        #pragma unroll
        for (int t = 0; t < 4; ++t) acc[t] = (floatx4){0.f, 0.f, 0.f, 0.f};

        #pragma unroll
        for (int kk = 0; kk < 2; ++kk) {
            short8 bfr;
            #pragma unroll
            for (int j = 0; j < 8; ++j) {
                int c = kk * 32 + quad * 8 + j;
                bfr[j] = (short)f2bf(x[(size_t)(b * 64 + c) * HWn + p]);
            }
            #pragma unroll
            for (int t = 0; t < 4; ++t)
                acc[t] = __builtin_amdgcn_mfma_f32_16x16x32_bf16(afr[t][kk], bfr, acc[t], 0, 0, 0);
        }

        __syncthreads();  // protect pack[] from previous iteration's readers
        #pragma unroll
        for (int t = 0; t < 4; ++t) {
            #pragma unroll
            for (int i = 0; i < 4; ++i) {
                int o = t * 16 + quad * 4 + i;
                float v = fmaf(acc[t][i], scs[o], shs[o]);
                v = v > 0.f ? v : 0.f;
                pack[(wv * 16 + m) * 88 + o] = f2bf(v);
            }
        }
        __syncthreads();
        // chunk-split store: wave = one chunk, lanes = 64 px -> 1-KB contiguous
        #pragma unroll
        for (int it = 0; it < 2; ++it) {
            int cid = it * 256 + tid;
            int chunk = cid >> 6, px = cid & 63;
            short8 vv = *(const short8*)(pack + px * 88 + chunk * 8);
            *(short8*)(node0 + ((size_t)(b * 8 + chunk) * HWn + p0 + px) * 8) = vv;
        }
        __syncthreads();
    }
}

// ---------------------------------------------------------------------------
// K2: cat[ch]=avgpool3, cat[ch+8]=maxpool5+maxpool3(avg).  Chunk-split I/O:
// lane stride 16 B -> ~1-KB contiguous loads/stores. Block = (b, 4-row band,
// chunk-half), 256 thr = 4 waves = 4 chunks. Rolling vertical rings.
// ---------------------------------------------------------------------------
__global__ __launch_bounds__(256) void k2_pools(
    const unsigned short* __restrict__ node0, unsigned short* __restrict__ cat)
{
    const int tid = threadIdx.x;
    const int lane = tid & 63;
    const int wv = tid >> 6;
    const int bid = blockIdx.x;
    const int half = bid & 1;
    const int band = (bid >> 1) % 14;
    const int b = bid / 28;
    const int chunk = half * 4 + wv;
    const int lo = band * 4;
    const int col = lane;
    const bool act = col < Wn;
    const unsigned short* base = node0 + ((size_t)(b * 8 + chunk) * HWn) * 8;
    unsigned short* cavg = cat + ((size_t)(b * 16 + chunk) * HWn) * 8;
    unsigned short* cmax = cat + ((size_t)(b * 16 + 8 + chunk) * HWn) * 8;

    float hs1[8], hs2[8], h5a[8], h5b[8], h5c[8], h5d[8], nh1[8], nh2[8];
    #pragma unroll
    for (int j = 0; j < 8; ++j) {
        hs1[j] = hs2[j] = 0.f;
        h5a[j] = h5b[j] = h5c[j] = h5d[j] = 0.f;
        nh1[j] = nh2[j] = 0.f;
    }

    for (int r = lo - 2; r <= lo + 5; ++r) {
        float v[5][8];
        #pragma unroll
        for (int d = 0; d < 5; ++d) {
            int cc = col + d - 2;
            bool ok = act && ((unsigned)cc < (unsigned)Wn) && ((unsigned)r < (unsigned)Hn);
            if (ok) {
                short8 ld = *(const short8*)(base + (size_t)(r * Wn + cc) * 8);
                #pragma unroll
                for (int j = 0; j < 8; ++j) v[d][j] = bf2f((unsigned short)ld[j]);
            } else {
                #pragma unroll
                for (int j = 0; j < 8; ++j) v[d][j] = 0.f;
            }
        }
        float a2[8], m5[8], m3[8];
        const int r2 = r - 1, r3 = r - 2;
        const bool v2 = (unsigned)r2 < (unsigned)Hn;
        #pragma unroll
        for (int j = 0; j < 8; ++j) {
            float hsum = v[1][j] + v[2][j] + v[3][j];
            float hm5 = fmaxf(fmaxf(fmaxf(v[0][j], v[1][j]), fmaxf(v[2][j], v[3][j])), v[4][j]);
            a2[j] = v2 ? (hs2[j] + hs1[j] + hsum) * (1.f / 9.f) : 0.f;
            hs2[j] = hs1[j]; hs1[j] = hsum;
            m5[j] = fmaxf(fmaxf(fmaxf(h5a[j], h5b[j]), fmaxf(h5c[j], h5d[j])), hm5);
            h5a[j] = h5b[j]; h5b[j] = h5c[j]; h5c[j] = h5d[j]; h5d[j] = hm5;
        }
        #pragma unroll
        for (int j = 0; j < 8; ++j) {
            float al = __shfl_up(a2[j], 1);   if (lane == 0)  al = 0.f;
            float ar = __shfl_down(a2[j], 1); if (lane == 63) ar = 0.f;
            float nh = fmaxf(fmaxf(al, a2[j]), ar);
            m3[j] = fmaxf(fmaxf(nh2[j], nh1[j]), nh);
            nh2[j] = nh1[j]; nh1[j] = nh;
        }
        if (act && r2 >= lo && r2 < lo + 4) {
            short8 st;
            #pragma unroll
            for (int j = 0; j < 8; ++j) st[j] = (short)f2bf(a2[j]);
            *(short8*)(cavg + (size_t)(r2 * Wn + col) * 8) = st;
        }
        if (act && r3 >= lo && r3 < lo + 4) {
            short8 st;
            #pragma unroll
            for (int j = 0; j < 8; ++j) st[j] = (short)f2bf(m5[j] + m3[j]);
            *(short8*)(cmax + (size_t)(r3 * Wn + col) * 8) = st;
        }
    }
}

// ---------------------------------------------------------------------------
// K3: out = relu(bn2(conv1x1(cat, w2))), 32x32x16 MFMA. D cols span 32 px ->
// out stores are full 128-B aligned lines (no write amplification). B-frags
// are 16-B contiguous chunk-split loads (512-B runs per half-wave).
// ---------------------------------------------------------------------------
__global__ __launch_bounds__(256) void k3_conv2(
    const unsigned short* __restrict__ cat, const float* __restrict__ w2,
    const float* __restrict__ bg, const float* __restrict__ bb,
    const float* __restrict__ bm, const float* __restrict__ bv,
    float* __restrict__ out)
{
    __shared__ float scs[64], shs[64];
    const int tid = threadIdx.x;
    if (tid < 64) {
        float sc = bg[tid] * rsqrtf(bv[tid] + EPS);
        scs[tid] = sc;
        shs[tid] = bb[tid] - bm[tid] * sc;
    }
    const int lane = tid & 63;
    const int wv = tid >> 6;
    const int n = lane & 31;   // px col within tile / o row within o-tile
    const int h = lane >> 5;   // k-half for A/B, +4 row offset for D

    // A-frags: w2[o][k], o = t*32 + n, k = kt*16 + h*8 + j
    short8 afr[2][8];
    #pragma unroll
    for (int t = 0; t < 2; ++t) {
        #pragma unroll
        for (int kt = 0; kt < 8; ++kt) {
            const float* wp = w2 + (t * 32 + n) * 128 + kt * 16 + h * 8;
            floatx4 f0 = *(const floatx4*)wp;
            floatx4 f1 = *(const floatx4*)(wp + 4);
            short8 s;
            s[0] = (short)f2bf(f0[0]); s[1] = (short)f2bf(f0[1]);
            s[2] = (short)f2bf(f0[2]); s[3] = (short)f2bf(f0[3]);
            s[4] = (short)f2bf(f1[0]); s[5] = (short)f2bf(f1[1]);
            s[6] = (short)f2bf(f1[2]); s[7] = (short)f2bf(f1[3]);
            afr[t][kt] = s;
        }
    }
    __syncthreads();

    const int tile = blockIdx.x * 4 + wv;       // 32-px tile; 3136%32==0, no b crossing
    const long Pl = (long)tile * 32;
    const int b = (int)(Pl / HWn);
    const int p0 = (int)(Pl - (long)b * HWn);

    floatx16 acc0 = {0.f}, acc1 = {0.f};
    #pragma unroll
    for (int i = 0; i < 16; ++i) { acc0[i] = 0.f; acc1[i] = 0.f; }

    #pragma unroll
    for (int kt = 0; kt < 8; ++kt) {
        short8 bfr = *(const short8*)(cat + ((size_t)(b * 16 + kt * 2 + h) * HWn + p0 + n) * 8);
        acc0 = __builtin_amdgcn_mfma_f32_32x32x16_bf16(afr[0][kt], bfr, acc0, 0, 0, 0);
        acc1 = __builtin_amdgcn_mfma_f32_32x32x16_bf16(afr[1][kt], bfr, acc1, 0, 0, 0);
    }

    float* ob = out + (size_t)b * 64 * HWn + p0 + n;
    #pragma unroll
    for (int r = 0; r < 16; ++r) {
        int o = (r & 3) + 8 * (r >> 2) + 4 * h;
        float v0 = fmaf(acc0[r], scs[o], shs[o]);
        ob[(size_t)o * HWn] = v0 > 0.f ? v0 : 0.f;
        float v1 = fmaf(acc1[r], scs[o + 32], shs[o + 32]);
        ob[(size_t)(o + 32) * HWn] = v1 > 0.f ? v1 : 0.f;
    }
}

extern "C" void kernel_launch(void* const* d_in, const int* in_sizes, int n_in,
                              void* d_out, int out_size, void* d_ws, size_t ws_size,
                              hipStream_t stream)
{
    const float* x   = (const float*)d_in[0];
    const float* w1  = (const float*)d_in[1];
    const float* w2  = (const float*)d_in[2];
    const float* b1g = (const float*)d_in[3];
    const float* b1b = (const float*)d_in[4];
    const float* b1m = (const float*)d_in[5];
    const float* b1v = (const float*)d_in[6];
    const float* b2g = (const float*)d_in[7];
    const float* b2b = (const float*)d_in[8];
    const float* b2m = (const float*)d_in[9];
    const float* b2v = (const float*)d_in[10];

    float* out = (float*)d_out;
    unsigned short* node0 = (unsigned short*)d_ws;            // 25.7 MB
    unsigned short* cat   = node0 + (size_t)Bn * HWn * 64;    // 51.4 MB

    k1_conv1<<<dim3(784), dim3(256), 0, stream>>>(x, w1, b1g, b1b, b1m, b1v, node0);
    k2_pools<<<dim3(Bn * 28), dim3(256), 0, stream>>>(node0, cat);
    k3_conv2<<<dim3(1568), dim3(256), 0, stream>>>(cat, w2, b2g, b2b, b2m, b2v, out);
}

// Round 5
// 165.413 us; speedup vs baseline: 1.7423x; 1.2288x over previous
//
#include <hip/hip_runtime.h>
#include <cstddef>

#define EPS 1e-5f
static constexpr int Bn = 64, Cn = 64, Hn = 56, Wn = 56, HWn = Hn * Wn; // 3136

typedef __attribute__((ext_vector_type(8))) short short8;
typedef __attribute__((ext_vector_type(8))) unsigned short ushort8;
typedef __attribute__((ext_vector_type(4))) float floatx4;
typedef __attribute__((ext_vector_type(16))) float floatx16;
typedef __attribute__((ext_vector_type(4))) unsigned int uintx4;
typedef __attribute__((ext_vector_type(2))) unsigned int uintx2;

// pack two fp32 -> two bf16 in one dword (lo = a, hi = b), round-to-nearest-even
__device__ __forceinline__ unsigned pack_rne(float a, float b) {
    unsigned ua = __float_as_uint(a), ub = __float_as_uint(b);
    ua = ua + 0x7fffu + ((ua >> 16) & 1u);
    ub = ub + 0x7fffu + ((ub >> 16) & 1u);
    return __builtin_amdgcn_perm(ub, ua, 0x07060302);
}
// truncating pack (1 op) — used only for MFMA input x
__device__ __forceinline__ unsigned pack_trunc(float a, float b) {
    return __builtin_amdgcn_perm(__float_as_uint(b), __float_as_uint(a), 0x07060302);
}
// packed u16 max (valid as bf16 max for non-negative values)
__device__ __forceinline__ ushort8 pmax(ushort8 a, ushort8 b) {
    return __builtin_elementwise_max(a, b);
}
__device__ __forceinline__ float bf_lo(unsigned u) { return __uint_as_float(u << 16); }
__device__ __forceinline__ float bf_hi(unsigned u) { return __uint_as_float(u & 0xffff0000u); }

// Layouts (bf16):
//   node0: [b][chunk=8][px=3136][j=8]
//   cat:   [b][chunk=16][px=3136][j=8]   ch 0-7 avg, 8-15 maxsum

// ---------------------------------------------------------------------------
// K1: node0 = relu(bn1(conv1x1(x,w1))). bn scale folded into A-frags.
// No LDS repack, no per-iter barriers: direct uint2 stores, dense 512-B runs
// per half-wave in chunk-split layout.
// ---------------------------------------------------------------------------
__global__ __launch_bounds__(256) void k1_conv1(
    const float* __restrict__ x, const float* __restrict__ w1,
    const float* __restrict__ bg, const float* __restrict__ bb,
    const float* __restrict__ bm, const float* __restrict__ bv,
    unsigned short* __restrict__ node0)
{
    __shared__ float scs[64], shs[64];
    const int tid = threadIdx.x;
    if (tid < 64) {
        float sc = bg[tid] * rsqrtf(bv[tid] + EPS);
        scs[tid] = sc;
        shs[tid] = bb[tid] - bm[tid] * sc;
    }
    __syncthreads();
    const int lane = tid & 63;
    const int wv   = tid >> 6;
    const int m    = lane & 15;
    const int quad = lane >> 4;

    // A-frags: rows o = t*16+m, k = kk*32 + quad*8 + j, scaled by bn sc[o]
    short8 afr[4][2];
    float shv[16];
    #pragma unroll
    for (int t = 0; t < 4; ++t) {
        const float sc = scs[t * 16 + m];
        #pragma unroll
        for (int kk = 0; kk < 2; ++kk) {
            const float* wp = w1 + (t * 16 + m) * 64 + kk * 32 + quad * 8;
            floatx4 f0 = *(const floatx4*)wp;
            floatx4 f1 = *(const floatx4*)(wp + 4);
            uintx4 u;
            u.x = pack_rne(f0[0] * sc, f0[1] * sc);
            u.y = pack_rne(f0[2] * sc, f0[3] * sc);
            u.z = pack_rne(f1[0] * sc, f1[1] * sc);
            u.w = pack_rne(f1[2] * sc, f1[3] * sc);
            afr[t][kk] = *(short8*)&u;
        }
        #pragma unroll
        for (int i = 0; i < 4; ++i) shv[t * 4 + i] = shs[t * 16 + quad * 4 + i];
    }

    #pragma unroll 1
    for (int tt = 0; tt < 4; ++tt) {
        const long P0 = (long)blockIdx.x * 256 + tt * 64; // 64-px group, 3136%64==0
        const int b = (int)(P0 / HWn);
        const int p0 = (int)(P0 - (long)b * HWn);
        const int p = p0 + wv * 16 + m;

        floatx4 acc[4];
        #pragma unroll
        for (int t = 0; t < 4; ++t) acc[t] = (floatx4){0.f, 0.f, 0.f, 0.f};

        #pragma unroll
        for (int kk = 0; kk < 2; ++kk) {
            float xv[8];
            #pragma unroll
            for (int j = 0; j < 8; ++j)
                xv[j] = x[(size_t)(b * 64 + kk * 32 + quad * 8 + j) * HWn + p];
            uintx4 u;
            u.x = pack_trunc(xv[0], xv[1]);
            u.y = pack_trunc(xv[2], xv[3]);
            u.z = pack_trunc(xv[4], xv[5]);
            u.w = pack_trunc(xv[6], xv[7]);
            short8 bfr = *(short8*)&u;
            #pragma unroll
            for (int t = 0; t < 4; ++t)
                acc[t] = __builtin_amdgcn_mfma_f32_16x16x32_bf16(afr[t][kk], bfr, acc[t], 0, 0, 0);
        }

        const int chunkbase = (quad >> 1);
        const int j0 = (quad & 1) * 4;
        #pragma unroll
        for (int t = 0; t < 4; ++t) {
            float v0 = acc[t][0] + shv[t * 4 + 0]; v0 = v0 > 0.f ? v0 : 0.f;
            float v1 = acc[t][1] + shv[t * 4 + 1]; v1 = v1 > 0.f ? v1 : 0.f;
            float v2 = acc[t][2] + shv[t * 4 + 2]; v2 = v2 > 0.f ? v2 : 0.f;
            float v3 = acc[t][3] + shv[t * 4 + 3]; v3 = v3 > 0.f ? v3 : 0.f;
            uintx2 st;
            st.x = pack_rne(v0, v1);
            st.y = pack_rne(v2, v3);
            int chunk = t * 2 + chunkbase;
            *(uintx2*)(node0 + ((size_t)(b * 8 + chunk) * HWn + p0 + wv * 16 + m) * 8 + j0) = st;
        }
    }
}

// ---------------------------------------------------------------------------
// K2: pools, packed-u16 max domain. Block = (b, 8-row band, chunk-half),
// 256 thr = 4 waves = 4 chunks. 5 packed loads/row; only center 3 unpacked.
// ---------------------------------------------------------------------------
__global__ __launch_bounds__(256) void k2_pools(
    const unsigned short* __restrict__ node0, unsigned short* __restrict__ cat)
{
    const int tid = threadIdx.x;
    const int lane = tid & 63;
    const int wv = tid >> 6;
    const int bid = blockIdx.x;
    const int half = bid & 1;
    const int band = (bid >> 1) % 7;
    const int b = bid / 14;
    const int chunk = half * 4 + wv;
    const int lo = band * 8;
    const int col = lane;
    const bool act = col < Wn;
    const unsigned short* base = node0 + ((size_t)(b * 8 + chunk) * HWn) * 8;
    unsigned short* cavg = cat + ((size_t)(b * 16 + chunk) * HWn) * 8;
    unsigned short* cmax = cat + ((size_t)(b * 16 + 8 + chunk) * HWn) * 8;

    const ushort8 zz = (ushort8)0;
    float hs1[8], hs2[8];
    ushort8 h5a = zz, h5b = zz, h5c = zz, h5d = zz, nh1 = zz, nh2 = zz;
    #pragma unroll
    for (int j = 0; j < 8; ++j) hs1[j] = hs2[j] = 0.f;

    #pragma unroll
    for (int r = lo - 2; r <= lo + 9; ++r) {
        ushort8 d[5];
        #pragma unroll
        for (int dd = 0; dd < 5; ++dd) {
            int cc = col + dd - 2;
            bool ok = act && ((unsigned)cc < (unsigned)Wn) && ((unsigned)r < (unsigned)Hn);
            d[dd] = ok ? *(const ushort8*)(base + (size_t)(r * Wn + cc) * 8) : zz;
        }
        // packed 5-col horizontal max
        ushort8 hm5 = pmax(pmax(pmax(d[0], d[1]), pmax(d[2], d[3])), d[4]);
        // rolling 5-row vertical max
        ushort8 m5 = pmax(pmax(pmax(h5a, h5b), pmax(h5c, h5d)), hm5);
        h5a = h5b; h5b = h5c; h5c = h5d; h5d = hm5;

        // unpack center 3 cols for avg
        const uintx4 ul = *(const uintx4*)&d[1];
        const uintx4 uv = *(const uintx4*)&d[2];
        const uintx4 ur = *(const uintx4*)&d[3];
        float a2[8];
        const int r2 = r - 1, r3 = r - 2;
        const bool v2 = (unsigned)r2 < (unsigned)Hn;
        #pragma unroll
        for (int w = 0; w < 4; ++w) {
            float l0 = bf_lo(ul[w]), l1 = bf_hi(ul[w]);
            float c0 = bf_lo(uv[w]), c1 = bf_hi(uv[w]);
            float r0 = bf_lo(ur[w]), r1 = bf_hi(ur[w]);
            float hsum0 = l0 + c0 + r0;
            float hsum1 = l1 + c1 + r1;
            a2[w * 2 + 0] = v2 ? (hs2[w * 2 + 0] + hs1[w * 2 + 0] + hsum0) * (1.f / 9.f) : 0.f;
            a2[w * 2 + 1] = v2 ? (hs2[w * 2 + 1] + hs1[w * 2 + 1] + hsum1) * (1.f / 9.f) : 0.f;
            hs2[w * 2 + 0] = hs1[w * 2 + 0]; hs1[w * 2 + 0] = hsum0;
            hs2[w * 2 + 1] = hs1[w * 2 + 1]; hs1[w * 2 + 1] = hsum1;
        }
        // pack a2 (RNE) once: reused for store and for maxpool3 chain
        uintx4 ap;
        ap.x = pack_rne(a2[0], a2[1]);
        ap.y = pack_rne(a2[2], a2[3]);
        ap.z = pack_rne(a2[4], a2[5]);
        ap.w = pack_rne(a2[6], a2[7]);
        // horizontal maxpool3 of packed a2 via shuffles
        uintx4 al, ar;
        #pragma unroll
        for (int w = 0; w < 4; ++w) {
            unsigned u = ap[w];
            unsigned lu = __shfl_up(u, 1);
            unsigned ru = __shfl_down(u, 1);
            al[w] = (lane == 0) ? 0u : lu;
            ar[w] = (lane == 63) ? 0u : ru;
        }
        ushort8 nh = pmax(pmax(*(ushort8*)&al, *(ushort8*)&ap), *(ushort8*)&ar);
        ushort8 m3 = pmax(pmax(nh2, nh1), nh);
        nh2 = nh1; nh1 = nh;

        if (act && r2 >= lo && r2 < lo + 8)
            *(uintx4*)(cavg + (size_t)(r2 * Wn + col) * 8) = ap;
        if (act && r3 >= lo && r3 < lo + 8) {
            const uintx4 u5 = *(const uintx4*)&m5;
            const uintx4 u3 = *(const uintx4*)&m3;
            uintx4 st;
            #pragma unroll
            for (int w = 0; w < 4; ++w)
                st[w] = pack_rne(bf_lo(u5[w]) + bf_lo(u3[w]), bf_hi(u5[w]) + bf_hi(u3[w]));
            *(uintx4*)(cmax + (size_t)(r3 * Wn + col) * 8) = st;
        }
    }
}

// ---------------------------------------------------------------------------
// K3: out = relu(bn2(conv1x1(cat,w2))), 32x32x16 MFMA. w2 staged once per
// block into LDS (bf16, frag-linear, conflict-free b128 reads); 2 tiles/wave.
// ---------------------------------------------------------------------------
__global__ __launch_bounds__(256) void k3_conv2(
    const unsigned short* __restrict__ cat, const float* __restrict__ w2,
    const float* __restrict__ bg, const float* __restrict__ bb,
    const float* __restrict__ bm, const float* __restrict__ bv,
    float* __restrict__ out)
{
    __shared__ unsigned short wl[1024 * 8];  // 16 KB frag-linear w2 (bf16)
    __shared__ float scs[64], shs[64];
    const int tid = threadIdx.x;
    if (tid < 64) {
        float sc = bg[tid] * rsqrtf(bv[tid] + EPS);
        scs[tid] = sc;
        shs[tid] = bb[tid] - bm[tid] * sc;
    }
    // stage w2 -> LDS: ci = (t*8+kt)*64 + lane_, 16 B per ci
    #pragma unroll
    for (int q = 0; q < 4; ++q) {
        int ci = tid * 4 + q;
        int lane_ = ci & 63, tk = ci >> 6;
        int t = tk >> 3, kt = tk & 7, n_ = lane_ & 31, h_ = lane_ >> 5;
        const float* wp = w2 + (t * 32 + n_) * 128 + kt * 16 + h_ * 8;
        floatx4 f0 = *(const floatx4*)wp;
        floatx4 f1 = *(const floatx4*)(wp + 4);
        uintx4 u;
        u.x = pack_rne(f0[0], f0[1]);
        u.y = pack_rne(f0[2], f0[3]);
        u.z = pack_rne(f1[0], f1[1]);
        u.w = pack_rne(f1[2], f1[3]);
        *(uintx4*)(wl + (size_t)ci * 8) = u;
    }
    __syncthreads();

    const int lane = tid & 63;
    const int wv = tid >> 6;
    const int n = lane & 31;
    const int h = lane >> 5;

    short8 afr[2][8];
    #pragma unroll
    for (int t = 0; t < 2; ++t)
        #pragma unroll
        for (int kt = 0; kt < 8; ++kt)
            afr[t][kt] = *(const short8*)(wl + ((size_t)((t * 8 + kt) * 64 + lane)) * 8);

    #pragma unroll 1
    for (int s = 0; s < 2; ++s) {
        const int tile = (blockIdx.x * 4 + wv) * 2 + s;   // 32-px tiles, 3136%32==0
        const int b = tile / 98;
        const int p0 = (tile - b * 98) * 32;

        floatx16 acc0, acc1;
        #pragma unroll
        for (int i = 0; i < 16; ++i) { acc0[i] = 0.f; acc1[i] = 0.f; }

        #pragma unroll
        for (int kt = 0; kt < 8; ++kt) {
            short8 bfr = *(const short8*)(cat + ((size_t)(b * 16 + kt * 2 + h) * HWn + p0 + n) * 8);
            acc0 = __builtin_amdgcn_mfma_f32_32x32x16_bf16(afr[0][kt], bfr, acc0, 0, 0, 0);
            acc1 = __builtin_amdgcn_mfma_f32_32x32x16_bf16(afr[1][kt], bfr, acc1, 0, 0, 0);
        }

        float* ob = out + (size_t)b * 64 * HWn + p0 + n;
        #pragma unroll
        for (int r = 0; r < 16; ++r) {
            int o = (r & 3) + 8 * (r >> 2) + 4 * h;
            float v0 = fmaf(acc0[r], scs[o], shs[o]);
            ob[(size_t)o * HWn] = v0 > 0.f ? v0 : 0.f;
            float v1 = fmaf(acc1[r], scs[o + 32], shs[o + 32]);
            ob[(size_t)(o + 32) * HWn] = v1 > 0.f ? v1 : 0.f;
        }
    }
}

extern "C" void kernel_launch(void* const* d_in, const int* in_sizes, int n_in,
                              void* d_out, int out_size, void* d_ws, size_t ws_size,
                              hipStream_t stream)
{
    const float* x   = (const float*)d_in[0];
    const float* w1  = (const float*)d_in[1];
    const float* w2  = (const float*)d_in[2];
    const float* b1g = (const float*)d_in[3];
    const float* b1b = (const float*)d_in[4];
    const float* b1m = (const float*)d_in[5];
    const float* b1v = (const float*)d_in[6];
    const float* b2g = (const float*)d_in[7];
    const float* b2b = (const float*)d_in[8];
    const float* b2m = (const float*)d_in[9];
    const float* b2v = (const float*)d_in[10];

    float* out = (float*)d_out;
    unsigned short* node0 = (unsigned short*)d_ws;            // 25.7 MB
    unsigned short* cat   = node0 + (size_t)Bn * HWn * 64;    // 51.4 MB

    k1_conv1<<<dim3(784), dim3(256), 0, stream>>>(x, w1, b1g, b1b, b1m, b1v, node0);
    k2_pools<<<dim3(Bn * 14), dim3(256), 0, stream>>>(node0, cat);
    k3_conv2<<<dim3(784), dim3(256), 0, stream>>>(cat, w2, b2g, b2b, b2m, b2v, out);
}